// Round 11
// baseline (264.183 us; speedup 1.0000x reference)
//
#include <hip/hip_runtime.h>

#define BSZ 4
#define NPATCH 256
#define DIM 384
#define HID 2688
#define NCLS 1000
#define KTOT 2048
#define IMGSZ 224
#define PCH 14
#define GRD 16

static constexpr float INV_BETA = 1.0f / 0.07f;
static constexpr float LN_EPS_F = 1e-6f;

typedef unsigned short u16;
typedef unsigned int   u32;
typedef __attribute__((ext_vector_type(8))) __bf16 bf16x8;
typedef __attribute__((ext_vector_type(4))) float  f32x4;

#define WAITVM(n) asm volatile("s_waitcnt vmcnt(" #n ")" ::: "memory")

__device__ __forceinline__ u16 f2bf(float f) {
    u32 u = __float_as_uint(f);
    return (u16)((u + 0x7FFFu + ((u >> 16) & 1u)) >> 16);
}
__device__ __forceinline__ float bf2f(u16 h) {
    return __uint_as_float(((u32)h) << 16);
}
__device__ __forceinline__ f32x4 mfma16(bf16x8 a, bf16x8 b, f32x4 c) {
    return __builtin_amdgcn_mfma_f32_16x16x32_bf16(a, b, c, 0, 0, 0);
}
__device__ __forceinline__ void gll16(const u16* g, u16* l) {
    __builtin_amdgcn_global_load_lds(
        (const __attribute__((address_space(1))) void*)g,
        (__attribute__((address_space(3))) void*)l, 16, 0, 0);
}
__device__ __forceinline__ bf16x8 ld8(const u16* p) {
    return *(const bf16x8*)p;
}
// bank swizzle (involution): 16B-granule col 0..3 XOR row bits 1-2; applied to
// the GLOBAL source column at staging and to the ds_read offset (rule #21).
__device__ __forceinline__ int swz(int row, int cseg) {
    return cseg ^ ((row >> 1) & 3);
}

// ---------------------------------------------------------------------------
// merged preprocessing
//  [0,768):       split feat -> Xhi/Xlo
//  [768,1776):    transpose+split fc1_w -> W1T [2688][384]
//  [1776,2784):   transpose+split fc2_w -> W2T [384][2688]
//  [2784,2848):   patch hist, one block per (b, grid-row py) -> LabT [b][c][256]
// ---------------------------------------------------------------------------
__device__ __forceinline__ void transpose_split_body(
    const float* __restrict__ In, int R, int C, int bx, int by,
    u16* __restrict__ OutHi, u16* __restrict__ OutLo, float (*tile)[33])
{
    int cx = bx * 32, ry = by * 32;
    int t = threadIdx.x;
    int tr = t >> 5, tc = t & 31;
    #pragma unroll
    for (int i = 0; i < 4; ++i)
        tile[tr + i * 8][tc] = In[(size_t)(ry + tr + i * 8) * C + cx + tc];
    __syncthreads();
    // vectorized transposed write: thread -> (out-row a, 4-col group seg)
    int a = t >> 3, seg = t & 7;
    u16 h4[4], l4[4];
    #pragma unroll
    for (int i = 0; i < 4; ++i) {
        float v = tile[seg * 4 + i][a];
        h4[i] = f2bf(v);
        l4[i] = f2bf(v - bf2f(h4[i]));
    }
    size_t off = (size_t)(cx + a) * R + ry + seg * 4;
    *(uint2*)(OutHi + off) = make_uint2((u32)h4[0] | ((u32)h4[1] << 16),
                                        (u32)h4[2] | ((u32)h4[3] << 16));
    *(uint2*)(OutLo + off) = make_uint2((u32)l4[0] | ((u32)l4[1] << 16),
                                        (u32)l4[2] | ((u32)l4[3] << 16));
}

__global__ __launch_bounds__(256) void prep_kernel(
    const float* __restrict__ Xt, const float* __restrict__ Xr,
    const float* __restrict__ fc1w, const float* __restrict__ fc2w,
    const int* __restrict__ labels,
    u16* __restrict__ Xhi, u16* __restrict__ Xlo,
    u16* __restrict__ W1Th, u16* __restrict__ W1Tl,
    u16* __restrict__ W2Th, u16* __restrict__ W2Tl,
    u16* __restrict__ LabT)
{
    __shared__ float tile[32][33];
    __shared__ int hist16[16][NCLS];          // 64 KB
    int blk = blockIdx.x, t = threadIdx.x;
    if (blk < 768) {
        int e = (blk * 256 + t) * 4;
        const float* src = (e < 1024 * DIM) ? (Xt + e) : (Xr + e - 1024 * DIM);
        float4 v = *(const float4*)src;
        float x[4] = {v.x, v.y, v.z, v.w};
        u16 h[4], l[4];
        #pragma unroll
        for (int i = 0; i < 4; ++i) {
            h[i] = f2bf(x[i]);
            l[i] = f2bf(x[i] - bf2f(h[i]));
        }
        *(uint2*)(Xhi + e) = make_uint2((u32)h[0] | ((u32)h[1] << 16), (u32)h[2] | ((u32)h[3] << 16));
        *(uint2*)(Xlo + e) = make_uint2((u32)l[0] | ((u32)l[1] << 16), (u32)l[2] | ((u32)l[3] << 16));
    } else if (blk < 1776) {
        int i = blk - 768;
        transpose_split_body(fc1w, DIM, HID, i % (HID / 32), i / (HID / 32), W1Th, W1Tl, tile);
    } else if (blk < 2784) {
        int i = blk - 1776;
        transpose_split_body(fc2w, HID, DIM, i % (DIM / 32), i / (DIM / 32), W2Th, W2Tl, tile);
    } else {
        int bp = blk - 2784;                   // 64 blocks: (b, py)
        int b = bp >> 4, py = bp & 15;
        for (int u = t; u < 16 * NCLS; u += 256) ((int*)hist16)[u] = 0;
        __syncthreads();
        const int* lrow = labels + (size_t)b * IMGSZ * IMGSZ + py * PCH * IMGSZ;
        for (int i = t; i < PCH * IMGSZ; i += 256) {     // coalesced loads
            int lab = lrow[i];
            int px = (i % IMGSZ) / PCH;
            atomicAdd(&hist16[px][lab], 1);
        }
        __syncthreads();
        const float inv = 1.0f / (PCH * PCH);
        for (int u = t; u < 16 * NCLS; u += 256) {       // 32B-granule writes
            int c = u >> 4, px = u & 15;
            LabT[((size_t)(b << 10) + c) * 256 + py * 16 + px] =
                f2bf(hist16[px][c] * inv);
        }
    }
}

// ---------------------------------------------------------------------------
// hi/lo GEMM: 128x64 block, 4 waves (2m x 2n), wave tile 64x32, BK=32,
// 3 LDS buffers, depth-2 prefetch, vmcnt(6).
// MODE 0: fc1 (+GELU -> Hhi/Hlo), XCD-swizzled grid
// MODE 1: fc2 -> f32 partials (split-K 4)
// ---------------------------------------------------------------------------
template<int MODE>
__global__ __launch_bounds__(256) void gemm64(
    const u16* __restrict__ Ahi, const u16* __restrict__ Alo,
    const u16* __restrict__ Bhi, const u16* __restrict__ Blo,
    const float* __restrict__ bias,
    u16* __restrict__ OutHi, u16* __restrict__ OutLo, float* __restrict__ OutF)
{
    constexpr int K  = (MODE == 1) ? HID : DIM;
    constexpr int KS = (MODE == 1) ? HID / 4 : K;
    constexpr int NT = KS / 32;
    constexpr int N  = (MODE == 0) ? HID : DIM;

    __shared__ u16 As_h[3][128 * 32];
    __shared__ u16 As_l[3][128 * 32];
    __shared__ u16 Bs_h[3][64 * 32];
    __shared__ u16 Bs_l[3][64 * 32];

    const int tid = threadIdx.x, lane = tid & 63, wid = tid >> 6;
    const int wm = wid >> 1, wn = wid & 1;
    int n0, m0;
    if constexpr (MODE == 0) {
        int s = (blockIdx.x & 7) * 84 + (blockIdx.x >> 3);   // 672 = 8*84
        n0 = (s % 42) * 64;
        m0 = (s / 42) * 128;
    } else {
        n0 = blockIdx.x * 64;
        m0 = blockIdx.y * 128;
    }

    const u16 *a_h, *a_l, *b_h, *b_l;
    if constexpr (MODE == 0) {
        a_h = Ahi + (size_t)m0 * K;   a_l = Alo + (size_t)m0 * K;
        b_h = Bhi + (size_t)n0 * K;   b_l = Blo + (size_t)n0 * K;
    } else {
        const int kbase = blockIdx.z * KS;
        a_h = Ahi + (size_t)m0 * K + kbase;   a_l = Alo + (size_t)m0 * K + kbase;
        b_h = Bhi + (size_t)n0 * K + kbase;   b_l = Blo + (size_t)n0 * K + kbase;
    }

    auto stage = [&](int buf, int k0) {
        #pragma unroll
        for (int j = 0; j < 2; ++j) {             // A: 128x32 = 512 granules
            int g = j * 256 + tid;
            int row = g >> 2, cs = g & 3;
            int col = swz(row, cs) << 3;
            gll16(a_h + (size_t)row * K + k0 + col, &As_h[buf][g * 8]);
            gll16(a_l + (size_t)row * K + k0 + col, &As_l[buf][g * 8]);
        }
        {                                          // B: 64x32 = 256 granules
            int row = tid >> 2, cs = tid & 3;
            int col = swz(row, cs) << 3;
            gll16(b_h + (size_t)row * K + k0 + col, &Bs_h[buf][tid * 8]);
            gll16(b_l + (size_t)row * K + k0 + col, &Bs_l[buf][tid * 8]);
        }
    };                                             // 6 gll16 / thread / stage

    const int l15 = lane & 15, cq = lane >> 4;
    int aoff[4], boff[2];
    #pragma unroll
    for (int i = 0; i < 4; ++i) {
        int ra = wm * 64 + i * 16 + l15;
        aoff[i] = ra * 32 + swz(ra, cq) * 8;
    }
    #pragma unroll
    for (int j = 0; j < 2; ++j) {
        int rb = wn * 32 + j * 16 + l15;
        boff[j] = rb * 32 + swz(rb, cq) * 8;
    }

    f32x4 acc[4][2] = {};

    auto compute = [&](int buf) {
        bf16x8 ah[4], al[4], bh[2], bl[2];
        #pragma unroll
        for (int i = 0; i < 4; ++i) {
            ah[i] = ld8(&As_h[buf][aoff[i]]);
            al[i] = ld8(&As_l[buf][aoff[i]]);
        }
        #pragma unroll
        for (int j = 0; j < 2; ++j) {
            bh[j] = ld8(&Bs_h[buf][boff[j]]);
            bl[j] = ld8(&Bs_l[buf][boff[j]]);
        }
        #pragma unroll
        for (int mi = 0; mi < 4; ++mi)
            #pragma unroll
            for (int ni = 0; ni < 2; ++ni) {
                acc[mi][ni] = mfma16(ah[mi], bh[ni], acc[mi][ni]);
                acc[mi][ni] = mfma16(ah[mi], bl[ni], acc[mi][ni]);
                acc[mi][ni] = mfma16(al[mi], bh[ni], acc[mi][ni]);
            }
    };

    stage(0, 0);
    stage(1, 32);
    int cur = 0;
    for (int t = 0; t < NT - 1; ++t) {
        WAITVM(6);
        __builtin_amdgcn_s_barrier();
        __builtin_amdgcn_sched_barrier(0);
        if (t + 2 < NT) {
            int nb = cur + 2; if (nb >= 3) nb -= 3;
            stage(nb, (t + 2) * 32);
        }
        compute(cur);
        cur = (cur == 2) ? 0 : cur + 1;
    }
    WAITVM(0);
    __builtin_amdgcn_s_barrier();
    __builtin_amdgcn_sched_barrier(0);
    compute(cur);

    #pragma unroll
    for (int mi = 0; mi < 4; ++mi)
        #pragma unroll
        for (int ni = 0; ni < 2; ++ni)
            #pragma unroll
            for (int r = 0; r < 4; ++r) {
                int gm = m0 + wm * 64 + mi * 16 + cq * 4 + r;
                int gn = n0 + wn * 32 + ni * 16 + l15;
                float v = acc[mi][ni][r];
                if constexpr (MODE == 0) {
                    v += bias[gn];
                    v = 0.5f * v * (1.0f + erff(v * 0.7071067811865476f));
                    u16 h = f2bf(v);
                    OutHi[(size_t)gm * N + gn] = h;
                    OutLo[(size_t)gm * N + gn] = f2bf(v - bf2f(h));
                } else {
                    OutF[(size_t)blockIdx.z * (2048 * DIM) + (size_t)gm * N + gn] = v;
                }
            }
}

// ---------------------------------------------------------------------------
// QK (pure-bf16 Z): 64x64 block, 4 waves (2m x 2n), wave tile 32x32,
// 3 LDS buffers (24KB), vmcnt(2).  E = exp((s-1)/beta) bf16, and folds
// the row-sum: per-wave 16-lane shuffle reduce -> f32 atomicAdd to R.
// ---------------------------------------------------------------------------
__global__ __launch_bounds__(256) void qk64(
    const u16* __restrict__ Z, const int* __restrict__ perms,
    u16* __restrict__ E, float* __restrict__ R)
{
    constexpr int NT = DIM / 32;
    __shared__ u16 As[3][64 * 32];
    __shared__ u16 Bs[3][64 * 32];

    const int tid = threadIdx.x, lane = tid & 63, wid = tid >> 6;
    const int wm = wid >> 1, wn = wid & 1;
    const int n0 = blockIdx.x * 64, m0 = blockIdx.y * 64, b = blockIdx.z;
    const int d = n0 >> 8;
    const int apd = (d == 0) ? b : perms[(d - 1) * BSZ + b];

    const u16* a_g = Z + (size_t)(b * NPATCH + m0) * DIM;
    const u16* b_g = Z + (size_t)(1024 + apd * NPATCH + (n0 & 255)) * DIM;

    auto stage = [&](int buf, int k0) {
        int row = tid >> 2, cs = tid & 3;
        int col = swz(row, cs) << 3;
        gll16(a_g + (size_t)row * DIM + k0 + col, &As[buf][tid * 8]);
        gll16(b_g + (size_t)row * DIM + k0 + col, &Bs[buf][tid * 8]);
    };                                             // 2 gll16 / thread / stage

    const int l15 = lane & 15, cq = lane >> 4;
    int aoff[2], boff[2];
    #pragma unroll
    for (int i = 0; i < 2; ++i) {
        int ra = wm * 32 + i * 16 + l15;
        aoff[i] = ra * 32 + swz(ra, cq) * 8;
        int rb = wn * 32 + i * 16 + l15;
        boff[i] = rb * 32 + swz(rb, cq) * 8;
    }

    f32x4 acc[2][2] = {};
    auto compute = [&](int buf) {
        bf16x8 a[2], bb[2];
        #pragma unroll
        for (int i = 0; i < 2; ++i) {
            a[i] = ld8(&As[buf][aoff[i]]);
            bb[i] = ld8(&Bs[buf][boff[i]]);
        }
        #pragma unroll
        for (int mi = 0; mi < 2; ++mi)
            #pragma unroll
            for (int ni = 0; ni < 2; ++ni)
                acc[mi][ni] = mfma16(a[mi], bb[ni], acc[mi][ni]);
    };

    stage(0, 0);
    stage(1, 32);
    int cur = 0;
    for (int t = 0; t < NT - 1; ++t) {
        WAITVM(2);
        __builtin_amdgcn_s_barrier();
        __builtin_amdgcn_sched_barrier(0);
        if (t + 2 < NT) {
            int nb = cur + 2; if (nb >= 3) nb -= 3;
            stage(nb, (t + 2) * 32);
        }
        compute(cur);
        cur = (cur == 2) ? 0 : cur + 1;
    }
    WAITVM(0);
    __builtin_amdgcn_s_barrier();
    __builtin_amdgcn_sched_barrier(0);
    compute(cur);

    float rp[2][4] = {};                           // row partials over this wave's 32 cols
    #pragma unroll
    for (int mi = 0; mi < 2; ++mi)
        #pragma unroll
        for (int ni = 0; ni < 2; ++ni)
            #pragma unroll
            for (int r = 0; r < 4; ++r) {
                int gm = m0 + wm * 32 + mi * 16 + cq * 4 + r;
                int gn = n0 + wn * 32 + ni * 16 + l15;
                float e = expf((acc[mi][ni][r] - 1.0f) * INV_BETA);
                u16 h = f2bf(e);
                E[((size_t)b * NPATCH + gm) * KTOT + gn] = h;
                rp[mi][r] += bf2f(h);              // sum the ROUNDED numerators
            }
    #pragma unroll
    for (int mi = 0; mi < 2; ++mi)
        #pragma unroll
        for (int r = 0; r < 4; ++r) {
            float v = rp[mi][r];
            #pragma unroll
            for (int off = 1; off < 16; off <<= 1) v += __shfl_xor(v, off);
            if (l15 == 0) {
                int gm = m0 + wm * 32 + mi * 16 + cq * 4 + r;
                atomicAdd(&R[(size_t)b * NPATCH + gm], v);
            }
        }
}

// ---------------------------------------------------------------------------
// PV: 128x64 block, 4 waves (2m x 2n), wave tile 64x32, single bf16,
// split-K 4 (z = ks*4 + b), 3 LDS buffers (36KB), vmcnt(3). 512 blocks.
// E * LabT-gather -> Lp f32 partials
// ---------------------------------------------------------------------------
__global__ __launch_bounds__(256) void pv64(
    const u16* __restrict__ E, const u16* __restrict__ LabT,
    const int* __restrict__ perms, float* __restrict__ Lp)
{
    constexpr int KSP = KTOT / 4;                 // 512
    constexpr int NT  = KSP / 32;                 // 16
    __shared__ u16 As[3][128 * 32];
    __shared__ u16 Bs[3][64 * 32];

    const int tid = threadIdx.x, lane = tid & 63, wid = tid >> 6;
    const int wm = wid >> 1, wn = wid & 1;
    const int n0 = blockIdx.x * 64, m0 = blockIdx.y * 128;
    const int b = blockIdx.z & 3, ks = blockIdx.z >> 2;
    const int s0 = ks * 2;
    const int apd0 = (s0 == 0) ? b : perms[(s0 - 1) * BSZ + b];
    const int apd1 = perms[s0 * BSZ + b];         // s0+1 >= 1 always

    const u16* abase = E + (size_t)(b * NPATCH + m0) * KTOT + ks * KSP;

    auto stage = [&](int buf, int k0) {
        #pragma unroll
        for (int j = 0; j < 2; ++j) {             // A: 128x32 = 512 granules
            int g = j * 256 + tid;
            int row = g >> 2, cs = g & 3;
            int col = swz(row, cs) << 3;
            gll16(abase + (size_t)row * KTOT + k0 + col, &As[buf][g * 8]);
        }
        {                                          // B: 64x32 = 256 granules
            int apd = (k0 & 256) ? apd1 : apd0;
            int p0 = k0 & 255;
            int row = tid >> 2, cs = tid & 3;
            int col = swz(row, cs) << 3;
            gll16(LabT + ((size_t)(apd << 10) + n0 + row) * 256 + p0 + col,
                  &Bs[buf][tid * 8]);
        }
    };                                             // 3 gll16 / thread / stage

    const int l15 = lane & 15, cq = lane >> 4;
    int aoff[4], boff[2];
    #pragma unroll
    for (int i = 0; i < 4; ++i) {
        int ra = wm * 64 + i * 16 + l15;
        aoff[i] = ra * 32 + swz(ra, cq) * 8;
    }
    #pragma unroll
    for (int j = 0; j < 2; ++j) {
        int rb = wn * 32 + j * 16 + l15;
        boff[j] = rb * 32 + swz(rb, cq) * 8;
    }

    f32x4 acc[4][2] = {};
    auto compute = [&](int buf) {
        bf16x8 a[4], bb[2];
        #pragma unroll
        for (int i = 0; i < 4; ++i) a[i] = ld8(&As[buf][aoff[i]]);
        #pragma unroll
        for (int j = 0; j < 2; ++j) bb[j] = ld8(&Bs[buf][boff[j]]);
        #pragma unroll
        for (int mi = 0; mi < 4; ++mi)
            #pragma unroll
            for (int ni = 0; ni < 2; ++ni)
                acc[mi][ni] = mfma16(a[mi], bb[ni], acc[mi][ni]);
    };

    stage(0, 0);
    stage(1, 32);
    int cur = 0;
    for (int t = 0; t < NT - 1; ++t) {
        WAITVM(3);
        __builtin_amdgcn_s_barrier();
        __builtin_amdgcn_sched_barrier(0);
        if (t + 2 < NT) {
            int nb = cur + 2; if (nb >= 3) nb -= 3;
            stage(nb, (t + 2) * 32);
        }
        compute(cur);
        cur = (cur == 2) ? 0 : cur + 1;
    }
    WAITVM(0);
    __builtin_amdgcn_s_barrier();
    __builtin_amdgcn_sched_barrier(0);
    compute(cur);

    #pragma unroll
    for (int mi = 0; mi < 4; ++mi)
        #pragma unroll
        for (int ni = 0; ni < 2; ++ni) {
            int gn = n0 + wn * 32 + ni * 16 + l15;
            if (gn < NCLS) {
                #pragma unroll
                for (int r = 0; r < 4; ++r) {
                    int gm = m0 + wm * 64 + mi * 16 + cq * 4 + r;
                    Lp[(((size_t)ks * BSZ + b) * NPATCH + gm) * NCLS + gn] =
                        acc[mi][ni][r];
                }
            }
        }
}

// ---------------------------------------------------------------------------
__device__ __forceinline__ float wave_sum(float v) {
    #pragma unroll
    for (int off = 32; off > 0; off >>= 1) v += __shfl_xor(v, off);
    return v;
}

__global__ __launch_bounds__(256) void ln_l2_kernel(
    const float* __restrict__ P0, const float* __restrict__ fc2b,
    const float* __restrict__ w, const float* __restrict__ b,
    u16* __restrict__ Zbf)
{
    const float* P1 = P0 + 1 * 2048 * DIM;
    const float* P2 = P0 + 2 * 2048 * DIM;
    const float* P3 = P0 + 3 * 2048 * DIM;
    int wid = threadIdx.x >> 6, lane = threadIdx.x & 63;
    int row = blockIdx.x * 4 + wid;
    size_t base = (size_t)row * DIM;
    float x[6];
    float s = 0.0f;
    #pragma unroll
    for (int i = 0; i < 6; ++i) {
        int c = lane + 64 * i;
        x[i] = ((P0[base + c] + P1[base + c]) + (P2[base + c] + P3[base + c])) + fc2b[c];
        s += x[i];
    }
    s = wave_sum(s);
    float mu = s * (1.0f / DIM);
    float vs = 0.0f;
    #pragma unroll
    for (int i = 0; i < 6; ++i) { float d = x[i] - mu; vs += d * d; }
    vs = wave_sum(vs);
    float rstd = 1.0f / sqrtf(vs * (1.0f / DIM) + LN_EPS_F);
    float z[6];
    float n2 = 0.0f;
    #pragma unroll
    for (int i = 0; i < 6; ++i) {
        z[i] = (x[i] - mu) * rstd * w[lane + 64 * i] + b[lane + 64 * i];
        n2 += z[i] * z[i];
    }
    n2 = wave_sum(n2);
    float inv = 1.0f / fmaxf(sqrtf(n2), 1e-12f);
    #pragma unroll
    for (int i = 0; i < 6; ++i)
        Zbf[base + lane + 64 * i] = f2bf(z[i] * inv);
}

// ---------------------------------------------------------------------------
// upsample: sums 4 split-K partials, divides by denominator, nt-stores
// ---------------------------------------------------------------------------
__global__ __launch_bounds__(256) void upsample_kernel(
    const float* __restrict__ Lp, const float* __restrict__ R,
    float* __restrict__ out)
{
    constexpr size_t S = (size_t)BSZ * NPATCH * NCLS;
    int blk = blockIdx.x;
    int gy = blk & 15;
    int bc = blk >> 4;
    int c = bc % NCLS;
    int b = bc / NCLS;
    __shared__ float vals[GRD];
    int t = threadIdx.x;
    if (t < GRD) {
        int q = b * NPATCH + gy * GRD + t;
        size_t i = (size_t)q * NCLS + c;
        vals[t] = ((Lp[i] + Lp[i + S]) + (Lp[i + 2 * S] + Lp[i + 3 * S])) / R[q];
    }
    __syncthreads();
    float* obase = out + ((size_t)(b * NCLS + c) * IMGSZ + gy * PCH) * IMGSZ;
    for (int idx = t; idx < PCH * 56; idx += 256) {
        int x4 = idx % 56, dy = idx / 56;
        int x0 = x4 * 4;
        f32x4 v = {vals[x0 / PCH], vals[(x0 + 1) / PCH],
                   vals[(x0 + 2) / PCH], vals[(x0 + 3) / PCH]};
        __builtin_nontemporal_store(v, (f32x4*)(obase + dy * IMGSZ + x0));
    }
}

// ---------------------------------------------------------------------------
extern "C" void kernel_launch(void* const* d_in, const int* in_sizes, int n_in,
                              void* d_out, int out_size, void* d_ws, size_t ws_size,
                              hipStream_t stream)
{
    (void)in_sizes; (void)n_in; (void)out_size; (void)ws_size;
    const float* feat_t = (const float*)d_in[0];
    const float* feat_r = (const float*)d_in[1];
    const int*   labels = (const int*)d_in[2];
    const int*   perms  = (const int*)d_in[3];
    const float* fc1_w  = (const float*)d_in[4];
    const float* fc1_b  = (const float*)d_in[5];
    const float* fc2_w  = (const float*)d_in[6];
    const float* fc2_b  = (const float*)d_in[7];
    const float* ln_w   = (const float*)d_in[8];
    const float* ln_b   = (const float*)d_in[9];
    float* out = (float*)d_out;
    char*  W   = (char*)d_ws;

    // workspace layout (bytes)
    u16*   Hhi  = (u16*)(W + 0);            // 11,010,048
    u16*   Hlo  = (u16*)(W + 11010048);     // -> 22,020,096
    u16*   E    = (u16*)(W + 0);            // 4,194,304 (aliases H, post-fc2)
    float* R    = (float*)(W + 4194304);    // 4,096
    float* Lp   = (float*)(W + 4718592);    // 4 x 4,096,000 -> 21,102,592
    float* P0   = (float*)(W + 22020096);   // 4 x 3,145,728
    u16*   Zbf  = (u16*)(W + 34603008);     // 1,572,864
    u16*   LabT = (u16*)(W + 37748736);     // 2,097,152
    u16*   Xhi  = (u16*)(W + 39845888);     // 1,572,864
    u16*   Xlo  = (u16*)(W + 41418752);     // 1,572,864
    u16*   W1Th = (u16*)(W + 42991616);     // 2,064,384
    u16*   W1Tl = (u16*)(W + 45056000);     // 2,064,384
    u16*   W2Th = (u16*)(W + 47120384);     // 2,064,384
    u16*   W2Tl = (u16*)(W + 49184768);     // 2,064,384

    prep_kernel<<<dim3(2848), dim3(256), 0, stream>>>(
        feat_t, feat_r, fc1_w, fc2_w, labels,
        Xhi, Xlo, W1Th, W1Tl, W2Th, W2Tl, LabT);

    gemm64<0><<<dim3(672), dim3(256), 0, stream>>>(
        Xhi, Xlo, W1Th, W1Tl, fc1_b, Hhi, Hlo, nullptr);

    gemm64<1><<<dim3(6, 16, 4), dim3(256), 0, stream>>>(
        Hhi, Hlo, W2Th, W2Tl, nullptr, nullptr, nullptr, P0);

    ln_l2_kernel<<<dim3(2048 / 4), dim3(256), 0, stream>>>(P0, fc2_b, ln_w, ln_b, Zbf);

    hipMemsetAsync(R, 0, BSZ * NPATCH * sizeof(float), stream);

    qk64<<<dim3(32, 4, 4), dim3(256), 0, stream>>>(Zbf, perms, E, R);

    pv64<<<dim3(16, 2, 16), dim3(256), 0, stream>>>(E, LabT, perms, Lp);

    upsample_kernel<<<dim3(BSZ * NCLS * GRD), dim3(256), 0, stream>>>(Lp, R, out);
}

// Round 12
// 226.143 us; speedup vs baseline: 1.1682x; 1.1682x over previous
//
#include <hip/hip_runtime.h>

#define BSZ 4
#define NPATCH 256
#define DIM 384
#define HID 2688
#define NCLS 1000
#define KTOT 2048
#define IMGSZ 224
#define PCH 14
#define GRD 16

static constexpr float INV_BETA = 1.0f / 0.07f;
static constexpr float LN_EPS_F = 1e-6f;

typedef unsigned short u16;
typedef unsigned int   u32;
typedef __attribute__((ext_vector_type(8))) __bf16 bf16x8;
typedef __attribute__((ext_vector_type(4))) float  f32x4;

#define WAITVM(n) asm volatile("s_waitcnt vmcnt(" #n ")" ::: "memory")

__device__ __forceinline__ u16 f2bf(float f) {
    u32 u = __float_as_uint(f);
    return (u16)((u + 0x7FFFu + ((u >> 16) & 1u)) >> 16);
}
__device__ __forceinline__ float bf2f(u16 h) {
    return __uint_as_float(((u32)h) << 16);
}
__device__ __forceinline__ f32x4 mfma16(bf16x8 a, bf16x8 b, f32x4 c) {
    return __builtin_amdgcn_mfma_f32_16x16x32_bf16(a, b, c, 0, 0, 0);
}
__device__ __forceinline__ void gll16(const u16* g, u16* l) {
    __builtin_amdgcn_global_load_lds(
        (const __attribute__((address_space(1))) void*)g,
        (__attribute__((address_space(3))) void*)l, 16, 0, 0);
}
__device__ __forceinline__ bf16x8 ld8(const u16* p) {
    return *(const bf16x8*)p;
}
// bank swizzle (involution): 16B-granule col 0..3 XOR row bits 1-2; applied to
// the GLOBAL source column at staging and to the ds_read offset (rule #21).
__device__ __forceinline__ int swz(int row, int cseg) {
    return cseg ^ ((row >> 1) & 3);
}

// ---------------------------------------------------------------------------
// merged preprocessing (all outputs now single bf16)
//  [0,768):       cast feat -> Xbf [2048][384]
//  [768,1776):    transpose fc1_w -> W1T [2688][384]
//  [1776,2784):   transpose fc2_w -> W2T [384][2688]
//  [2784,2848):   patch hist, one block per (b, grid-row py) -> LabT [b][c][256]
// ---------------------------------------------------------------------------
__device__ __forceinline__ void transpose_cast_body(
    const float* __restrict__ In, int R, int C, int bx, int by,
    u16* __restrict__ OutT, float (*tile)[33])
{
    int cx = bx * 32, ry = by * 32;
    int t = threadIdx.x;
    int tr = t >> 5, tc = t & 31;
    #pragma unroll
    for (int i = 0; i < 4; ++i)
        tile[tr + i * 8][tc] = In[(size_t)(ry + tr + i * 8) * C + cx + tc];
    __syncthreads();
    int a = t >> 3, seg = t & 7;
    u16 h4[4];
    #pragma unroll
    for (int i = 0; i < 4; ++i)
        h4[i] = f2bf(tile[seg * 4 + i][a]);
    size_t off = (size_t)(cx + a) * R + ry + seg * 4;
    *(uint2*)(OutT + off) = make_uint2((u32)h4[0] | ((u32)h4[1] << 16),
                                       (u32)h4[2] | ((u32)h4[3] << 16));
}

__global__ __launch_bounds__(256) void prep_kernel(
    const float* __restrict__ Xt, const float* __restrict__ Xr,
    const float* __restrict__ fc1w, const float* __restrict__ fc2w,
    const int* __restrict__ labels,
    u16* __restrict__ Xbf, u16* __restrict__ W1T, u16* __restrict__ W2T,
    u16* __restrict__ LabT)
{
    __shared__ float tile[32][33];
    __shared__ int hist16[16][NCLS];          // 64 KB
    int blk = blockIdx.x, t = threadIdx.x;
    if (blk < 768) {
        int e = (blk * 256 + t) * 4;
        const float* src = (e < 1024 * DIM) ? (Xt + e) : (Xr + e - 1024 * DIM);
        float4 v = *(const float4*)src;
        u16 h[4] = {f2bf(v.x), f2bf(v.y), f2bf(v.z), f2bf(v.w)};
        *(uint2*)(Xbf + e) = make_uint2((u32)h[0] | ((u32)h[1] << 16),
                                        (u32)h[2] | ((u32)h[3] << 16));
    } else if (blk < 1776) {
        int i = blk - 768;
        transpose_cast_body(fc1w, DIM, HID, i % (HID / 32), i / (HID / 32), W1T, tile);
    } else if (blk < 2784) {
        int i = blk - 1776;
        transpose_cast_body(fc2w, HID, DIM, i % (DIM / 32), i / (DIM / 32), W2T, tile);
    } else {
        int bp = blk - 2784;                   // 64 blocks: (b, py)
        int b = bp >> 4, py = bp & 15;
        for (int u = t; u < 16 * NCLS; u += 256) ((int*)hist16)[u] = 0;
        __syncthreads();
        const int* lrow = labels + (size_t)b * IMGSZ * IMGSZ + py * PCH * IMGSZ;
        for (int i = t; i < PCH * IMGSZ; i += 256) {     // coalesced loads
            int lab = lrow[i];
            int px = (i % IMGSZ) / PCH;
            atomicAdd(&hist16[px][lab], 1);
        }
        __syncthreads();
        const float inv = 1.0f / (PCH * PCH);
        for (int u = t; u < 16 * NCLS; u += 256) {       // 32B-granule writes
            int c = u >> 4, px = u & 15;
            LabT[((size_t)(b << 10) + c) * 256 + py * 16 + px] =
                f2bf(hist16[px][c] * inv);
        }
    }
}

// ---------------------------------------------------------------------------
// pure-bf16 GEMM: 128x64 block, 4 waves (2m x 2n), wave tile 64x32, BK=32,
// 3 LDS buffers (36KB -> 4 blocks/CU), depth-2 prefetch, vmcnt(3).
// MODE 0: fc1  X*W1T + b -> GELU -> H bf16, XCD-swizzled grid
// MODE 1: fc2  H*W2T -> f32 partials (split-K 4)
// ---------------------------------------------------------------------------
template<int MODE>
__global__ __launch_bounds__(256) void gemm64(
    const u16* __restrict__ A_g, const u16* __restrict__ B_g,
    const float* __restrict__ bias,
    u16* __restrict__ OutB, float* __restrict__ OutF)
{
    constexpr int K  = (MODE == 1) ? HID : DIM;
    constexpr int KS = (MODE == 1) ? HID / 4 : K;
    constexpr int NT = KS / 32;
    constexpr int N  = (MODE == 0) ? HID : DIM;

    __shared__ u16 As[3][128 * 32];
    __shared__ u16 Bs[3][64 * 32];

    const int tid = threadIdx.x, lane = tid & 63, wid = tid >> 6;
    const int wm = wid >> 1, wn = wid & 1;
    int n0, m0;
    if constexpr (MODE == 0) {
        int s = (blockIdx.x & 7) * 84 + (blockIdx.x >> 3);   // 672 = 8*84
        n0 = (s % 42) * 64;
        m0 = (s / 42) * 128;
    } else {
        n0 = blockIdx.x * 64;
        m0 = blockIdx.y * 128;
    }

    const int kbase = (MODE == 1) ? blockIdx.z * KS : 0;
    const u16* a_g = A_g + (size_t)m0 * K + kbase;
    const u16* b_g = B_g + (size_t)n0 * K + kbase;

    auto stage = [&](int buf, int k0) {
        #pragma unroll
        for (int j = 0; j < 2; ++j) {             // A: 128x32 = 512 granules
            int g = j * 256 + tid;
            int row = g >> 2, cs = g & 3;
            int col = swz(row, cs) << 3;
            gll16(a_g + (size_t)row * K + k0 + col, &As[buf][g * 8]);
        }
        {                                          // B: 64x32 = 256 granules
            int row = tid >> 2, cs = tid & 3;
            int col = swz(row, cs) << 3;
            gll16(b_g + (size_t)row * K + k0 + col, &Bs[buf][tid * 8]);
        }
    };                                             // 3 gll16 / thread / stage

    const int l15 = lane & 15, cq = lane >> 4;
    int aoff[4], boff[2];
    #pragma unroll
    for (int i = 0; i < 4; ++i) {
        int ra = wm * 64 + i * 16 + l15;
        aoff[i] = ra * 32 + swz(ra, cq) * 8;
    }
    #pragma unroll
    for (int j = 0; j < 2; ++j) {
        int rb = wn * 32 + j * 16 + l15;
        boff[j] = rb * 32 + swz(rb, cq) * 8;
    }

    f32x4 acc[4][2] = {};

    auto compute = [&](int buf) {
        bf16x8 a[4], bb[2];
        #pragma unroll
        for (int i = 0; i < 4; ++i) a[i] = ld8(&As[buf][aoff[i]]);
        #pragma unroll
        for (int j = 0; j < 2; ++j) bb[j] = ld8(&Bs[buf][boff[j]]);
        #pragma unroll
        for (int mi = 0; mi < 4; ++mi)
            #pragma unroll
            for (int ni = 0; ni < 2; ++ni)
                acc[mi][ni] = mfma16(a[mi], bb[ni], acc[mi][ni]);
    };

    stage(0, 0);
    stage(1, 32);
    int cur = 0;
    for (int t = 0; t < NT - 1; ++t) {
        WAITVM(3);
        __builtin_amdgcn_s_barrier();
        __builtin_amdgcn_sched_barrier(0);
        if (t + 2 < NT) {
            int nb = cur + 2; if (nb >= 3) nb -= 3;
            stage(nb, (t + 2) * 32);
        }
        compute(cur);
        cur = (cur == 2) ? 0 : cur + 1;
    }
    WAITVM(0);
    __builtin_amdgcn_s_barrier();
    __builtin_amdgcn_sched_barrier(0);
    compute(cur);

    #pragma unroll
    for (int mi = 0; mi < 4; ++mi)
        #pragma unroll
        for (int ni = 0; ni < 2; ++ni)
            #pragma unroll
            for (int r = 0; r < 4; ++r) {
                int gm = m0 + wm * 64 + mi * 16 + cq * 4 + r;
                int gn = n0 + wn * 32 + ni * 16 + l15;
                float v = acc[mi][ni][r];
                if constexpr (MODE == 0) {
                    v += bias[gn];
                    v = 0.5f * v * (1.0f + erff(v * 0.7071067811865476f));
                    OutB[(size_t)gm * N + gn] = f2bf(v);
                } else {
                    OutF[(size_t)blockIdx.z * (2048 * DIM) + (size_t)gm * N + gn] = v;
                }
            }
}

// ---------------------------------------------------------------------------
// QK (pure-bf16 Z): 64x64 block, 4 waves (2m x 2n), wave tile 32x32,
// 3 LDS buffers (24KB), vmcnt(2).  E = exp((s-1)/beta) bf16, and folds
// the row-sum: per-wave 16-lane shuffle reduce -> f32 atomicAdd to R.
// ---------------------------------------------------------------------------
__global__ __launch_bounds__(256) void qk64(
    const u16* __restrict__ Z, const int* __restrict__ perms,
    u16* __restrict__ E, float* __restrict__ R)
{
    constexpr int NT = DIM / 32;
    __shared__ u16 As[3][64 * 32];
    __shared__ u16 Bs[3][64 * 32];

    const int tid = threadIdx.x, lane = tid & 63, wid = tid >> 6;
    const int wm = wid >> 1, wn = wid & 1;
    const int n0 = blockIdx.x * 64, m0 = blockIdx.y * 64, b = blockIdx.z;
    const int d = n0 >> 8;
    const int apd = (d == 0) ? b : perms[(d - 1) * BSZ + b];

    const u16* a_g = Z + (size_t)(b * NPATCH + m0) * DIM;
    const u16* b_g = Z + (size_t)(1024 + apd * NPATCH + (n0 & 255)) * DIM;

    auto stage = [&](int buf, int k0) {
        int row = tid >> 2, cs = tid & 3;
        int col = swz(row, cs) << 3;
        gll16(a_g + (size_t)row * DIM + k0 + col, &As[buf][tid * 8]);
        gll16(b_g + (size_t)row * DIM + k0 + col, &Bs[buf][tid * 8]);
    };                                             // 2 gll16 / thread / stage

    const int l15 = lane & 15, cq = lane >> 4;
    int aoff[2], boff[2];
    #pragma unroll
    for (int i = 0; i < 2; ++i) {
        int ra = wm * 32 + i * 16 + l15;
        aoff[i] = ra * 32 + swz(ra, cq) * 8;
        int rb = wn * 32 + i * 16 + l15;
        boff[i] = rb * 32 + swz(rb, cq) * 8;
    }

    f32x4 acc[2][2] = {};
    auto compute = [&](int buf) {
        bf16x8 a[2], bb[2];
        #pragma unroll
        for (int i = 0; i < 2; ++i) {
            a[i] = ld8(&As[buf][aoff[i]]);
            bb[i] = ld8(&Bs[buf][boff[i]]);
        }
        #pragma unroll
        for (int mi = 0; mi < 2; ++mi)
            #pragma unroll
            for (int ni = 0; ni < 2; ++ni)
                acc[mi][ni] = mfma16(a[mi], bb[ni], acc[mi][ni]);
    };

    stage(0, 0);
    stage(1, 32);
    int cur = 0;
    for (int t = 0; t < NT - 1; ++t) {
        WAITVM(2);
        __builtin_amdgcn_s_barrier();
        __builtin_amdgcn_sched_barrier(0);
        if (t + 2 < NT) {
            int nb = cur + 2; if (nb >= 3) nb -= 3;
            stage(nb, (t + 2) * 32);
        }
        compute(cur);
        cur = (cur == 2) ? 0 : cur + 1;
    }
    WAITVM(0);
    __builtin_amdgcn_s_barrier();
    __builtin_amdgcn_sched_barrier(0);
    compute(cur);

    float rp[2][4] = {};                           // row partials over this wave's 32 cols
    #pragma unroll
    for (int mi = 0; mi < 2; ++mi)
        #pragma unroll
        for (int ni = 0; ni < 2; ++ni)
            #pragma unroll
            for (int r = 0; r < 4; ++r) {
                int gm = m0 + wm * 32 + mi * 16 + cq * 4 + r;
                int gn = n0 + wn * 32 + ni * 16 + l15;
                float e = expf((acc[mi][ni][r] - 1.0f) * INV_BETA);
                u16 h = f2bf(e);
                E[((size_t)b * NPATCH + gm) * KTOT + gn] = h;
                rp[mi][r] += bf2f(h);              // sum the ROUNDED numerators
            }
    #pragma unroll
    for (int mi = 0; mi < 2; ++mi)
        #pragma unroll
        for (int r = 0; r < 4; ++r) {
            float v = rp[mi][r];
            #pragma unroll
            for (int off = 1; off < 16; off <<= 1) v += __shfl_xor(v, off);
            if (l15 == 0) {
                int gm = m0 + wm * 32 + mi * 16 + cq * 4 + r;
                atomicAdd(&R[(size_t)b * NPATCH + gm], v);
            }
        }
}

// ---------------------------------------------------------------------------
// PV: 128x64 block, 4 waves (2m x 2n), wave tile 64x32, single bf16,
// split-K 4 (z = ks*4 + b), 3 LDS buffers (36KB), vmcnt(3). 512 blocks.
// E * LabT-gather -> Lp f32 partials
// ---------------------------------------------------------------------------
__global__ __launch_bounds__(256) void pv64(
    const u16* __restrict__ E, const u16* __restrict__ LabT,
    const int* __restrict__ perms, float* __restrict__ Lp)
{
    constexpr int KSP = KTOT / 4;                 // 512
    constexpr int NT  = KSP / 32;                 // 16
    __shared__ u16 As[3][128 * 32];
    __shared__ u16 Bs[3][64 * 32];

    const int tid = threadIdx.x, lane = tid & 63, wid = tid >> 6;
    const int wm = wid >> 1, wn = wid & 1;
    const int n0 = blockIdx.x * 64, m0 = blockIdx.y * 128;
    const int b = blockIdx.z & 3, ks = blockIdx.z >> 2;
    const int s0 = ks * 2;
    const int apd0 = (s0 == 0) ? b : perms[(s0 - 1) * BSZ + b];
    const int apd1 = perms[s0 * BSZ + b];         // s0+1 >= 1 always

    const u16* abase = E + (size_t)(b * NPATCH + m0) * KTOT + ks * KSP;

    auto stage = [&](int buf, int k0) {
        #pragma unroll
        for (int j = 0; j < 2; ++j) {             // A: 128x32 = 512 granules
            int g = j * 256 + tid;
            int row = g >> 2, cs = g & 3;
            int col = swz(row, cs) << 3;
            gll16(abase + (size_t)row * KTOT + k0 + col, &As[buf][g * 8]);
        }
        {                                          // B: 64x32 = 256 granules
            int apd = (k0 & 256) ? apd1 : apd0;
            int p0 = k0 & 255;
            int row = tid >> 2, cs = tid & 3;
            int col = swz(row, cs) << 3;
            gll16(LabT + ((size_t)(apd << 10) + n0 + row) * 256 + p0 + col,
                  &Bs[buf][tid * 8]);
        }
    };                                             // 3 gll16 / thread / stage

    const int l15 = lane & 15, cq = lane >> 4;
    int aoff[4], boff[2];
    #pragma unroll
    for (int i = 0; i < 4; ++i) {
        int ra = wm * 64 + i * 16 + l15;
        aoff[i] = ra * 32 + swz(ra, cq) * 8;
    }
    #pragma unroll
    for (int j = 0; j < 2; ++j) {
        int rb = wn * 32 + j * 16 + l15;
        boff[j] = rb * 32 + swz(rb, cq) * 8;
    }

    f32x4 acc[4][2] = {};
    auto compute = [&](int buf) {
        bf16x8 a[4], bb[2];
        #pragma unroll
        for (int i = 0; i < 4; ++i) a[i] = ld8(&As[buf][aoff[i]]);
        #pragma unroll
        for (int j = 0; j < 2; ++j) bb[j] = ld8(&Bs[buf][boff[j]]);
        #pragma unroll
        for (int mi = 0; mi < 4; ++mi)
            #pragma unroll
            for (int ni = 0; ni < 2; ++ni)
                acc[mi][ni] = mfma16(a[mi], bb[ni], acc[mi][ni]);
    };

    stage(0, 0);
    stage(1, 32);
    int cur = 0;
    for (int t = 0; t < NT - 1; ++t) {
        WAITVM(3);
        __builtin_amdgcn_s_barrier();
        __builtin_amdgcn_sched_barrier(0);
        if (t + 2 < NT) {
            int nb = cur + 2; if (nb >= 3) nb -= 3;
            stage(nb, (t + 2) * 32);
        }
        compute(cur);
        cur = (cur == 2) ? 0 : cur + 1;
    }
    WAITVM(0);
    __builtin_amdgcn_s_barrier();
    __builtin_amdgcn_sched_barrier(0);
    compute(cur);

    #pragma unroll
    for (int mi = 0; mi < 4; ++mi)
        #pragma unroll
        for (int ni = 0; ni < 2; ++ni) {
            int gn = n0 + wn * 32 + ni * 16 + l15;
            if (gn < NCLS) {
                #pragma unroll
                for (int r = 0; r < 4; ++r) {
                    int gm = m0 + wm * 64 + mi * 16 + cq * 4 + r;
                    Lp[(((size_t)ks * BSZ + b) * NPATCH + gm) * NCLS + gn] =
                        acc[mi][ni][r];
                }
            }
        }
}

// ---------------------------------------------------------------------------
__device__ __forceinline__ float wave_sum(float v) {
    #pragma unroll
    for (int off = 32; off > 0; off >>= 1) v += __shfl_xor(v, off);
    return v;
}

// split-K(4) reduce + bias + LayerNorm + L2 -> Zbf; also zeroes R (rows<1024)
__global__ __launch_bounds__(256) void ln_l2_kernel(
    const float* __restrict__ P0, const float* __restrict__ fc2b,
    const float* __restrict__ w, const float* __restrict__ b,
    u16* __restrict__ Zbf, float* __restrict__ R)
{
    if (blockIdx.x < 256 && threadIdx.x < 4)
        R[blockIdx.x * 4 + threadIdx.x] = 0.0f;
    const float* P1 = P0 + 1 * 2048 * DIM;
    const float* P2 = P0 + 2 * 2048 * DIM;
    const float* P3 = P0 + 3 * 2048 * DIM;
    int wid = threadIdx.x >> 6, lane = threadIdx.x & 63;
    int row = blockIdx.x * 4 + wid;
    size_t base = (size_t)row * DIM;
    float x[6];
    float s = 0.0f;
    #pragma unroll
    for (int i = 0; i < 6; ++i) {
        int c = lane + 64 * i;
        x[i] = ((P0[base + c] + P1[base + c]) + (P2[base + c] + P3[base + c])) + fc2b[c];
        s += x[i];
    }
    s = wave_sum(s);
    float mu = s * (1.0f / DIM);
    float vs = 0.0f;
    #pragma unroll
    for (int i = 0; i < 6; ++i) { float d = x[i] - mu; vs += d * d; }
    vs = wave_sum(vs);
    float rstd = 1.0f / sqrtf(vs * (1.0f / DIM) + LN_EPS_F);
    float z[6];
    float n2 = 0.0f;
    #pragma unroll
    for (int i = 0; i < 6; ++i) {
        z[i] = (x[i] - mu) * rstd * w[lane + 64 * i] + b[lane + 64 * i];
        n2 += z[i] * z[i];
    }
    n2 = wave_sum(n2);
    float inv = 1.0f / fmaxf(sqrtf(n2), 1e-12f);
    #pragma unroll
    for (int i = 0; i < 6; ++i)
        Zbf[base + lane + 64 * i] = f2bf(z[i] * inv);
}

// ---------------------------------------------------------------------------
// upsample: sums 4 split-K partials, divides by denominator, nt-stores
// ---------------------------------------------------------------------------
__global__ __launch_bounds__(256) void upsample_kernel(
    const float* __restrict__ Lp, const float* __restrict__ R,
    float* __restrict__ out)
{
    constexpr size_t S = (size_t)BSZ * NPATCH * NCLS;
    int blk = blockIdx.x;
    int gy = blk & 15;
    int bc = blk >> 4;
    int c = bc % NCLS;
    int b = bc / NCLS;
    __shared__ float vals[GRD];
    int t = threadIdx.x;
    if (t < GRD) {
        int q = b * NPATCH + gy * GRD + t;
        size_t i = (size_t)q * NCLS + c;
        vals[t] = ((Lp[i] + Lp[i + S]) + (Lp[i + 2 * S] + Lp[i + 3 * S])) / R[q];
    }
    __syncthreads();
    float* obase = out + ((size_t)(b * NCLS + c) * IMGSZ + gy * PCH) * IMGSZ;
    for (int idx = t; idx < PCH * 56; idx += 256) {
        int x4 = idx % 56, dy = idx / 56;
        int x0 = x4 * 4;
        f32x4 v = {vals[x0 / PCH], vals[(x0 + 1) / PCH],
                   vals[(x0 + 2) / PCH], vals[(x0 + 3) / PCH]};
        __builtin_nontemporal_store(v, (f32x4*)(obase + dy * IMGSZ + x0));
    }
}

// ---------------------------------------------------------------------------
extern "C" void kernel_launch(void* const* d_in, const int* in_sizes, int n_in,
                              void* d_out, int out_size, void* d_ws, size_t ws_size,
                              hipStream_t stream)
{
    (void)in_sizes; (void)n_in; (void)out_size; (void)ws_size;
    const float* feat_t = (const float*)d_in[0];
    const float* feat_r = (const float*)d_in[1];
    const int*   labels = (const int*)d_in[2];
    const int*   perms  = (const int*)d_in[3];
    const float* fc1_w  = (const float*)d_in[4];
    const float* fc1_b  = (const float*)d_in[5];
    const float* fc2_w  = (const float*)d_in[6];
    const float* fc2_b  = (const float*)d_in[7];
    const float* ln_w   = (const float*)d_in[8];
    const float* ln_b   = (const float*)d_in[9];
    float* out = (float*)d_out;
    char*  W   = (char*)d_ws;

    // workspace layout (bytes)
    u16*   H    = (u16*)(W + 0);            // 11,010,048 (bf16)
    u16*   E    = (u16*)(W + 0);            // 4,194,304 (aliases H, post-fc2)
    float* R    = (float*)(W + 4194304);    // 4,096
    float* Lp   = (float*)(W + 4718592);    // 4 x 4,096,000 -> 21,102,592
    float* P0   = (float*)(W + 22020096);   // 4 x 3,145,728 -> 34,603,008
    u16*   Zbf  = (u16*)(W + 34603008);     // 1,572,864
    u16*   LabT = (u16*)(W + 37748736);     // 2,097,152
    u16*   Xbf  = (u16*)(W + 39845888);     // 1,572,864
    u16*   W1T  = (u16*)(W + 42991616);     // 2,064,384
    u16*   W2T  = (u16*)(W + 47120384);     // 2,064,384

    prep_kernel<<<dim3(2848), dim3(256), 0, stream>>>(
        feat_t, feat_r, fc1_w, fc2_w, labels, Xbf, W1T, W2T, LabT);

    gemm64<0><<<dim3(672), dim3(256), 0, stream>>>(
        Xbf, W1T, fc1_b, H, nullptr);

    gemm64<1><<<dim3(6, 16, 4), dim3(256), 0, stream>>>(
        H, W2T, nullptr, nullptr, P0);

    ln_l2_kernel<<<dim3(2048 / 4), dim3(256), 0, stream>>>(
        P0, fc2_b, ln_w, ln_b, Zbf, R);

    qk64<<<dim3(32, 4, 4), dim3(256), 0, stream>>>(Zbf, perms, E, R);

    pv64<<<dim3(16, 2, 16), dim3(256), 0, stream>>>(E, LabT, perms, Lp);

    upsample_kernel<<<dim3(BSZ * NCLS * GRD), dim3(256), 0, stream>>>(Lp, R, out);
}